// Round 6
// baseline (4502.203 us; speedup 1.0000x reference)
//
#include <hip/hip_runtime.h>
#include <hip/hip_fp16.h>

#define B_  64
#define T_  2048
#define I_  64
#define H_  256
#define G4_ 1024   // 4*H

typedef _Float16 h2v __attribute__((ext_vector_type(2)));

__device__ __forceinline__ float fdot2(uint32_t a, uint32_t b, float c) {
#if __has_builtin(__builtin_amdgcn_fdot2)
    return __builtin_amdgcn_fdot2(__builtin_bit_cast(h2v, a), __builtin_bit_cast(h2v, b), c, false);
#else
    h2v ha = __builtin_bit_cast(h2v, a), hb = __builtin_bit_cast(h2v, b);
    return c + (float)ha.x * (float)hb.x + (float)ha.y * (float)hb.y;
#endif
}

__device__ __forceinline__ ushort f2h(float v) {
    return __builtin_bit_cast(ushort, (_Float16)v);
}
__device__ __forceinline__ float h2f(ushort v) {
    return (float)__builtin_bit_cast(_Float16, v);
}

// ---------------------------------------------------------------------------
// Repack W_hh fp32 [1024][256] -> f16 wpk[g][kc][h][j]  (g=gate, kc=K/8 chunk,
// h=hdim 0..255, j=0..7).  Coalesced 16B/lane preload in the LSTM kernel.
// ---------------------------------------------------------------------------
__global__ void repack_kernel(const float* __restrict__ Whh, ushort* __restrict__ wpk) {
    int o  = blockIdx.x * 256 + threadIdx.x;   // 0 .. 262143
    int j  = o & 7;
    int h  = (o >> 3) & 255;
    int kc = (o >> 11) & 31;
    int g  = o >> 16;
    float v = Whh[(g * 256 + h) * 256 + kc * 8 + j];
    wpk[o] = f2h(v);
}

// ---------------------------------------------------------------------------
// gx2 = x @ W_ih^T + b_ih + b_hh, TRANSPOSED f16 layout [bt][hd][gate] so the
// lstm kernel fetches one ushort4 per (t,hd).  grid = ((64*TCc)/32, 4).
// ---------------------------------------------------------------------------
__global__ __launch_bounds__(256) void gx_kernel(
    const float* __restrict__ x, const float* __restrict__ Wih,
    const float* __restrict__ bih, const float* __restrict__ bhh,
    ushort* __restrict__ gx2, int t0, int TCc) {

    __shared__ float xs[32][64];
    const int bt0 = blockIdx.x * 32;
    const int gq  = blockIdx.y;                 // gate 0..3
    const int row = gq * 256 + threadIdx.x;     // W_ih row

    for (int i = threadIdx.x; i < 512; i += 256) {
        int r  = i >> 4, c4 = i & 15;
        int bt = bt0 + r;
        int b  = bt / TCc;
        int tl = bt - b * TCc;
        *(float4*)(&xs[r][c4 * 4]) =
            *(const float4*)(&x[(((size_t)b * T_) + t0 + tl) * I_ + c4 * 4]);
    }
    __syncthreads();

    float w[64];
#pragma unroll
    for (int k = 0; k < 64; ++k) w[k] = Wih[row * I_ + k];
    const float bias = bih[row] + bhh[row];

    for (int i = 0; i < 32; ++i) {
        float acc = bias;
#pragma unroll
        for (int k4 = 0; k4 < 16; ++k4) {
            float4 xq = *(const float4*)(&xs[i][k4 * 4]);
            acc = fmaf(w[k4 * 4 + 0], xq.x, acc);
            acc = fmaf(w[k4 * 4 + 1], xq.y, acc);
            acc = fmaf(w[k4 * 4 + 2], xq.z, acc);
            acc = fmaf(w[k4 * 4 + 3], xq.w, acc);
        }
        gx2[((size_t)(bt0 + i) * 256 + threadIdx.x) * 4 + gq] = f2h(acc);
    }
}

// ---------------------------------------------------------------------------
// Persistent per-batch LSTM.  64 blocks x 1024 threads, waves_per_eu(4,4)
// => 128-VGPR budget.  Wave w: q = w>>2 (K-quarter, WAVE-UNIFORM -- round-5
// lesson: per-lane q made the hq broadcast 4-address and cost +4 cyc/read),
// hd = (w&3)*64 + lane.  i/f/g K-quarters in regs (96 dw, fits 128 budget:
// round-4/5 lesson), o K-quarter streamed from LDS (128 KB, XOR-swizzled).
// Quarter partials: q!=0 write float4 to pex; q0 waves reduce + elementwise
// (wave-uniform branch).  2 barriers/step.
// ---------------------------------------------------------------------------
__global__ __attribute__((amdgpu_flat_work_group_size(1024, 1024), amdgpu_waves_per_eu(4, 4)))
void lstm_kernel(
    const ushort* __restrict__ wpk, const ushort* __restrict__ gx2,
    ushort* __restrict__ hbuf,     // [B][TCc][H] f16
    float* __restrict__ state,     // [2][64][256]: c then h
    int TCc, int first) {

    __shared__ __align__(16) ushort wg4[256 * 256];   // o-gate rows, 128 KB
    __shared__ __align__(16) ushort hs[2][256];       // h dbuf (f16)
    __shared__ __align__(16) float  pex[3][256][4];   // q=1..3 -> q=0 partials, 12 KB

    const int tid  = threadIdx.x;
    const int wid  = tid >> 6;
    const int q    = wid >> 2;               // K-quarter, wave-uniform
    const int hd   = (wid & 3) * 64 + (tid & 63);
    const int hm   = hd & 31;
    const int b    = blockIdx.x;
    const bool q0  = (q == 0);

    // --- preload i/f/g K-quarters into registers (16B/lane, coalesced) ---
    uint32_t wi[32], wf[32], wg[32];
#pragma unroll
    for (int k = 0; k < 8; ++k) {
        uint4 v = *(const uint4*)(wpk + (size_t)(0 * 32 + q * 8 + k) * 2048 + hd * 8);
        wi[k * 4 + 0] = v.x; wi[k * 4 + 1] = v.y; wi[k * 4 + 2] = v.z; wi[k * 4 + 3] = v.w;
    }
#pragma unroll
    for (int k = 0; k < 8; ++k) {
        uint4 v = *(const uint4*)(wpk + (size_t)(1 * 32 + q * 8 + k) * 2048 + hd * 8);
        wf[k * 4 + 0] = v.x; wf[k * 4 + 1] = v.y; wf[k * 4 + 2] = v.z; wf[k * 4 + 3] = v.w;
    }
#pragma unroll
    for (int k = 0; k < 8; ++k) {
        uint4 v = *(const uint4*)(wpk + (size_t)(2 * 32 + q * 8 + k) * 2048 + hd * 8);
        wg[k * 4 + 0] = v.x; wg[k * 4 + 1] = v.y; wg[k * 4 + 2] = v.z; wg[k * 4 + 3] = v.w;
    }
    // --- o-gate K-quarter -> LDS [hd][u], u = kc ^ (hd&31) (proven 0-conflict) ---
#pragma unroll
    for (int k = 0; k < 8; ++k) {
        uint4 v = *(const uint4*)(wpk + (size_t)(3 * 32 + q * 8 + k) * 2048 + hd * 8);
        int u = (q * 8 + k) ^ hm;
        *(uint4*)(wg4 + hd * 256 + u * 8) = v;
    }

    float c = 0.f, h = 0.f;
    if (q0) {
        if (!first) {
            c = state[b * H_ + hd];
            h = state[B_ * H_ + b * H_ + hd];
        }
        hs[0][hd] = f2h(h);
    }
    __syncthreads();

    const ushort* gxb = gx2 + (size_t)b * TCc * G4_;
    ushort* hb = hbuf + (size_t)b * TCc * H_;

    ushort4 cg;
    if (q0) cg = *(const ushort4*)(gxb + (size_t)0 * G4_ + hd * 4);

    for (int tl = 0; tl < TCc; ++tl) {
        // prefetch next step's gates (q0 only; hidden under the dot loop)
        ushort4 ng;
        if (q0) {
            const int tn = (tl + 1 < TCc) ? tl + 1 : tl;
            ng = *(const ushort4*)(gxb + (size_t)tn * G4_ + hd * 4);
        }

        const ushort* hsr = hs[tl & 1];
        float ai = 0.f, af = 0.f, agv = 0.f, ao = 0.f;

#pragma unroll
        for (int k = 0; k < 8; ++k) {
            const int kc = q * 8 + k;
            uint4 hq = *(const uint4*)(hsr + kc * 8);            // wave-uniform bcast
            int u = kc ^ hm;
            uint4 wo = *(const uint4*)(wg4 + hd * 256 + u * 8);  // per-lane stream
            ai  = fdot2(wi[k * 4 + 0], hq.x, ai);
            ai  = fdot2(wi[k * 4 + 1], hq.y, ai);
            ai  = fdot2(wi[k * 4 + 2], hq.z, ai);
            ai  = fdot2(wi[k * 4 + 3], hq.w, ai);
            af  = fdot2(wf[k * 4 + 0], hq.x, af);
            af  = fdot2(wf[k * 4 + 1], hq.y, af);
            af  = fdot2(wf[k * 4 + 2], hq.z, af);
            af  = fdot2(wf[k * 4 + 3], hq.w, af);
            agv = fdot2(wg[k * 4 + 0], hq.x, agv);
            agv = fdot2(wg[k * 4 + 1], hq.y, agv);
            agv = fdot2(wg[k * 4 + 2], hq.z, agv);
            agv = fdot2(wg[k * 4 + 3], hq.w, agv);
            ao  = fdot2(wo.x, hq.x, ao);
            ao  = fdot2(wo.y, hq.y, ao);
            ao  = fdot2(wo.z, hq.z, ao);
            ao  = fdot2(wo.w, hq.w, ao);
        }

        if (!q0) {
            float4 p; p.x = ai; p.y = af; p.z = agv; p.w = ao;
            *(float4*)(&pex[q - 1][hd][0]) = p;
        }
        __syncthreads();

        if (q0) {
            float4 p0 = *(const float4*)(&pex[0][hd][0]);
            ai += p0.x; af += p0.y; agv += p0.z; ao += p0.w;
            float4 p1 = *(const float4*)(&pex[1][hd][0]);
            ai += p1.x; af += p1.y; agv += p1.z; ao += p1.w;
            float4 p2 = *(const float4*)(&pex[2][hd][0]);
            ai += p2.x; af += p2.y; agv += p2.z; ao += p2.w;

            ai += h2f(cg.x); af += h2f(cg.y); agv += h2f(cg.z); ao += h2f(cg.w);

            float si = __builtin_amdgcn_rcpf(1.f + __expf(-ai));
            float sf = __builtin_amdgcn_rcpf(1.f + __expf(-af));
            float so = __builtin_amdgcn_rcpf(1.f + __expf(-ao));
            float eg = __expf(2.f * agv);
            float tg = (eg - 1.f) * __builtin_amdgcn_rcpf(eg + 1.f);
            c = sf * c + si * tg;
            float ec = __expf(2.f * c);
            float tc = (ec - 1.f) * __builtin_amdgcn_rcpf(ec + 1.f);
            h = so * tc;

            ushort hh = f2h(h);
            hs[(tl + 1) & 1][hd] = hh;
            hb[(size_t)tl * H_ + hd] = hh;
            cg = ng;
        }
        __syncthreads();
    }

    if (q0) {
        state[b * H_ + hd]           = c;
        state[B_ * H_ + b * H_ + hd] = h;
    }
}

// ---------------------------------------------------------------------------
// out[b,t] = sum_hd h[b,t,hd] * Wo[hd] + bo.  h f16 rows, fully dense reads.
// ---------------------------------------------------------------------------
__global__ __launch_bounds__(256) void proj_kernel(
    const ushort* __restrict__ hbuf, const float* __restrict__ Wo,
    const float* __restrict__ bo, float* __restrict__ out, int t0, int TCc) {

    const int lane = threadIdx.x & 63;
    const int wid  = blockIdx.x * 4 + (threadIdx.x >> 6);
    const int nw   = gridDim.x * 4;
    const int rows = B_ * TCc;

    float4 w = *(const float4*)(Wo + lane * 4);
    const float bov = bo[0];

    for (int r = wid; r < rows; r += nw) {
        const ushort* hp = hbuf + (size_t)r * H_ + lane * 4;
        ushort4 u = *(const ushort4*)hp;
        float p = h2f(u.x) * w.x + h2f(u.y) * w.y + h2f(u.z) * w.z + h2f(u.w) * w.w;
#pragma unroll
        for (int m = 1; m < 64; m <<= 1) p += __shfl_xor(p, m, 64);
        if (lane == 0) {
            int b  = r / TCc;
            int tl = r - b * TCc;
            out[(size_t)b * T_ + t0 + tl] = p + bov;
        }
    }
}

// ---------------------------------------------------------------------------
extern "C" void kernel_launch(void* const* d_in, const int* in_sizes, int n_in,
                              void* d_out, int out_size, void* d_ws, size_t ws_size,
                              hipStream_t stream) {
    const float* x   = (const float*)d_in[0];
    const float* Wih = (const float*)d_in[1];
    const float* Whh = (const float*)d_in[2];
    const float* bih = (const float*)d_in[3];
    const float* bhh = (const float*)d_in[4];
    const float* Wo  = (const float*)d_in[5];
    const float* bo  = (const float*)d_in[6];
    float* out = (float*)d_out;

    char* ws = (char*)d_ws;
    ushort* wpk   = (ushort*)ws;                              // 512 KB
    float*  state = (float*)(ws + 512 * 1024);                // 128 KB
    char*   dyn   = ws + 640 * 1024;                          // gx2 + hbuf chunks

    size_t avail = (ws_size > 640 * 1024) ? ws_size - 640 * 1024 : 0;
    // per (b,t): gx2 row 2048 B + hbuf row 512 B
    long long tcmax = (long long)(avail / ((size_t)B_ * (G4_ + H_) * 2));
    // Cap chunks at 512 steps so gx2 (64MB) + hbuf (16MB) stay L3-resident.
    int TC = (tcmax > 512) ? 512 : (int)tcmax;
    TC &= ~63;               // multiple of 64
    if (TC < 64) TC = 64;    // minimum viable chunk

    repack_kernel<<<1024, 256, 0, stream>>>(Whh, wpk);

    for (int t0 = 0; t0 < T_; t0 += TC) {
        int TCc = (T_ - t0 < TC) ? (T_ - t0) : TC;
        ushort* gxb  = (ushort*)dyn;
        ushort* hbuf = (ushort*)(dyn + (size_t)B_ * TCc * G4_ * 2);
        dim3 g1((B_ * TCc) / 32, 4);
        gx_kernel<<<g1, 256, 0, stream>>>(x, Wih, bih, bhh, gxb, t0, TCc);
        lstm_kernel<<<B_, 1024, 0, stream>>>(wpk, gxb, hbuf, state, TCc, t0 == 0 ? 1 : 0);
        proj_kernel<<<256, 256, 0, stream>>>(hbuf, Wo, bo, out, t0, TCc);
    }
    (void)in_sizes; (void)n_in; (void)out_size;
}

// Round 7
// 3759.242 us; speedup vs baseline: 1.1976x; 1.1976x over previous
//
#include <hip/hip_runtime.h>
#include <hip/hip_fp16.h>

#define B_  64
#define T_  2048
#define I_  64
#define H_  256
#define G4_ 1024   // 4*H

typedef _Float16 h2v __attribute__((ext_vector_type(2)));

__device__ __forceinline__ float fdot2(uint32_t a, uint32_t b, float c) {
#if __has_builtin(__builtin_amdgcn_fdot2)
    return __builtin_amdgcn_fdot2(__builtin_bit_cast(h2v, a), __builtin_bit_cast(h2v, b), c, false);
#else
    h2v ha = __builtin_bit_cast(h2v, a), hb = __builtin_bit_cast(h2v, b);
    return c + (float)ha.x * (float)hb.x + (float)ha.y * (float)hb.y;
#endif
}

__device__ __forceinline__ ushort f2h(float v) {
    return __builtin_bit_cast(ushort, (_Float16)v);
}
__device__ __forceinline__ float h2f(ushort v) {
    return (float)__builtin_bit_cast(_Float16, v);
}

// ---------------------------------------------------------------------------
// Repack W_hh fp32 [1024][256] -> f16 wpk[g][kc][h][j]  (g=gate, kc=K/8 chunk,
// h=hdim 0..255, j=0..7).  Coalesced 16B/lane preload in the LSTM kernel.
// ---------------------------------------------------------------------------
__global__ void repack_kernel(const float* __restrict__ Whh, ushort* __restrict__ wpk) {
    int o  = blockIdx.x * 256 + threadIdx.x;   // 0 .. 262143
    int j  = o & 7;
    int h  = (o >> 3) & 255;
    int kc = (o >> 11) & 31;
    int g  = o >> 16;
    float v = Whh[(g * 256 + h) * 256 + kc * 8 + j];
    wpk[o] = f2h(v);
}

// ---------------------------------------------------------------------------
// gx2 = x @ W_ih^T + b_ih + b_hh, TRANSPOSED f16 layout [bt][hd][gate] so the
// lstm kernel fetches one ushort4 per (t,hd).  grid = ((64*TCc)/32, 4).
// ---------------------------------------------------------------------------
__global__ __launch_bounds__(256) void gx_kernel(
    const float* __restrict__ x, const float* __restrict__ Wih,
    const float* __restrict__ bih, const float* __restrict__ bhh,
    ushort* __restrict__ gx2, int t0, int TCc) {

    __shared__ float xs[32][64];
    const int bt0 = blockIdx.x * 32;
    const int gq  = blockIdx.y;                 // gate 0..3 (i,f,g,o)
    const int row = gq * 256 + threadIdx.x;     // W_ih row

    for (int i = threadIdx.x; i < 512; i += 256) {
        int r  = i >> 4, c4 = i & 15;
        int bt = bt0 + r;
        int b  = bt / TCc;
        int tl = bt - b * TCc;
        *(float4*)(&xs[r][c4 * 4]) =
            *(const float4*)(&x[(((size_t)b * T_) + t0 + tl) * I_ + c4 * 4]);
    }
    __syncthreads();

    float w[64];
#pragma unroll
    for (int k = 0; k < 64; ++k) w[k] = Wih[row * I_ + k];
    const float bias = bih[row] + bhh[row];

    for (int i = 0; i < 32; ++i) {
        float acc = bias;
#pragma unroll
        for (int k4 = 0; k4 < 16; ++k4) {
            float4 xq = *(const float4*)(&xs[i][k4 * 4]);
            acc = fmaf(w[k4 * 4 + 0], xq.x, acc);
            acc = fmaf(w[k4 * 4 + 1], xq.y, acc);
            acc = fmaf(w[k4 * 4 + 2], xq.z, acc);
            acc = fmaf(w[k4 * 4 + 3], xq.w, acc);
        }
        gx2[((size_t)(bt0 + i) * 256 + threadIdx.x) * 4 + gq] = f2h(acc);
    }
}

// ---------------------------------------------------------------------------
// Persistent per-batch LSTM.  64 blocks x 512 threads (8 waves, 1 block/CU by
// LDS -> 2 waves/SIMD).  NO waves_per_eu attribute: rounds 3-6 showed any
// explicit occupancy pin makes the allocator split the budget 50/50 arch/acc
// (r3: 128 arch, r6: 64 arch -> AGPR move tax).  Round 1 (no attribute) got
// 228 arch VGPRs: the allocator follows LDS-implied occupancy.  Pressure here
// ~= 208 weight dwords + ~32 working <= 256 arch cap.
// Thread pair (hd, hd+256) splits K=256 (q = tid>>8).
// Regs: i/f/g half-rows (192 dw) + last 4 kc of o half-row (16 dw).
// LDS: first 12 kc of o half-rows [kc'][q][hd][8] (1KB-contiguous wave reads,
// 0 conflicts measured in r4).  q=1 hands partials to q=0 via packed float4.
// ---------------------------------------------------------------------------
__global__ __attribute__((amdgpu_flat_work_group_size(512, 512)))
void lstm_kernel(
    const ushort* __restrict__ wpk, const ushort* __restrict__ gx2,
    ushort* __restrict__ hbuf,     // [B][TCc][H] f16
    float* __restrict__ state,     // [2][64][256]: c then h
    int TCc, int first) {

    __shared__ __align__(16) ushort wg4[12 * 2 * 256 * 8]; // o-gate stream, 96 KB
    __shared__ __align__(16) ushort hs[256];               // h(t-1) as f16
    __shared__ __align__(16) float pex[256][4];            // q=1 -> q=0 partials

    const int tid   = threadIdx.x;
    const int hd    = tid & 255;       // owned h-dim
    const int q     = tid >> 8;        // K-half: 0 -> kc 0..15, 1 -> kc 16..31
    const int kbase = q << 4;
    const int b     = blockIdx.x;
    const bool q0   = (q == 0);

    // --- preload i/f/g gate half-rows into registers (16B/lane, coalesced) ---
    uint32_t wi[64], wf[64], wg[64];
#pragma unroll
    for (int k = 0; k < 16; ++k) {
        uint4 v = *(const uint4*)(wpk + (size_t)(0 * 32 + kbase + k) * 2048 + hd * 8);
        wi[k * 4 + 0] = v.x; wi[k * 4 + 1] = v.y; wi[k * 4 + 2] = v.z; wi[k * 4 + 3] = v.w;
    }
#pragma unroll
    for (int k = 0; k < 16; ++k) {
        uint4 v = *(const uint4*)(wpk + (size_t)(1 * 32 + kbase + k) * 2048 + hd * 8);
        wf[k * 4 + 0] = v.x; wf[k * 4 + 1] = v.y; wf[k * 4 + 2] = v.z; wf[k * 4 + 3] = v.w;
    }
#pragma unroll
    for (int k = 0; k < 16; ++k) {
        uint4 v = *(const uint4*)(wpk + (size_t)(2 * 32 + kbase + k) * 2048 + hd * 8);
        wg[k * 4 + 0] = v.x; wg[k * 4 + 1] = v.y; wg[k * 4 + 2] = v.z; wg[k * 4 + 3] = v.w;
    }
    // --- o-gate: first 12 kc -> LDS [kc'][q][hd][8]; last 4 kc -> registers ---
#pragma unroll
    for (int k = 0; k < 12; ++k) {
        uint4 v = *(const uint4*)(wpk + (size_t)(3 * 32 + kbase + k) * 2048 + hd * 8);
        *(uint4*)(wg4 + ((k * 2 + q) * 256 + hd) * 8) = v;
    }
    uint32_t wo_r[16];
#pragma unroll
    for (int k = 0; k < 4; ++k) {
        uint4 v = *(const uint4*)(wpk + (size_t)(3 * 32 + kbase + 12 + k) * 2048 + hd * 8);
        wo_r[k * 4 + 0] = v.x; wo_r[k * 4 + 1] = v.y; wo_r[k * 4 + 2] = v.z; wo_r[k * 4 + 3] = v.w;
    }

    float c = 0.f, h = 0.f;
    if (q0) {
        if (!first) {
            c = state[b * H_ + hd];
            h = state[B_ * H_ + b * H_ + hd];
        }
        hs[hd] = f2h(h);
    }
    __syncthreads();

    const ushort* gxb = gx2 + (size_t)b * TCc * G4_;
    ushort* hb = hbuf + (size_t)b * TCc * H_;

    ushort4 cg;
    if (q0) cg = *(const ushort4*)(gxb + (size_t)0 * G4_ + hd * 4);

    for (int tl = 0; tl < TCc; ++tl) {
        // prefetch next step's gates (q0 only; hidden under the dot loop)
        ushort4 ng;
        if (q0) {
            const int tn = (tl + 1 < TCc) ? tl + 1 : tl;
            ng = *(const ushort4*)(gxb + (size_t)tn * G4_ + hd * 4);
        }

        float ai = 0.f, af = 0.f, agv = 0.f, ao = 0.f;

        // --- kc 0..11 of this half: o-weights stream from LDS ---
#pragma unroll
        for (int k = 0; k < 12; ++k) {
            const int kc = kbase + k;
            uint4 hq = *(const uint4*)(hs + kc * 8);                        // bcast
            uint4 wo = *(const uint4*)(wg4 + ((k * 2 + q) * 256 + hd) * 8); // stream
            ai  = fdot2(wi[k * 4 + 0], hq.x, ai);
            ai  = fdot2(wi[k * 4 + 1], hq.y, ai);
            ai  = fdot2(wi[k * 4 + 2], hq.z, ai);
            ai  = fdot2(wi[k * 4 + 3], hq.w, ai);
            af  = fdot2(wf[k * 4 + 0], hq.x, af);
            af  = fdot2(wf[k * 4 + 1], hq.y, af);
            af  = fdot2(wf[k * 4 + 2], hq.z, af);
            af  = fdot2(wf[k * 4 + 3], hq.w, af);
            agv = fdot2(wg[k * 4 + 0], hq.x, agv);
            agv = fdot2(wg[k * 4 + 1], hq.y, agv);
            agv = fdot2(wg[k * 4 + 2], hq.z, agv);
            agv = fdot2(wg[k * 4 + 3], hq.w, agv);
            ao  = fdot2(wo.x, hq.x, ao);
            ao  = fdot2(wo.y, hq.y, ao);
            ao  = fdot2(wo.z, hq.z, ao);
            ao  = fdot2(wo.w, hq.w, ao);
        }
        // --- kc 12..15 of this half: o-weights from registers ---
#pragma unroll
        for (int k = 12; k < 16; ++k) {
            const int kc = kbase + k;
            const int r  = (k - 12) * 4;
            uint4 hq = *(const uint4*)(hs + kc * 8);
            ai  = fdot2(wi[k * 4 + 0], hq.x, ai);
            ai  = fdot2(wi[k * 4 + 1], hq.y, ai);
            ai  = fdot2(wi[k * 4 + 2], hq.z, ai);
            ai  = fdot2(wi[k * 4 + 3], hq.w, ai);
            af  = fdot2(wf[k * 4 + 0], hq.x, af);
            af  = fdot2(wf[k * 4 + 1], hq.y, af);
            af  = fdot2(wf[k * 4 + 2], hq.z, af);
            af  = fdot2(wf[k * 4 + 3], hq.w, af);
            agv = fdot2(wg[k * 4 + 0], hq.x, agv);
            agv = fdot2(wg[k * 4 + 1], hq.y, agv);
            agv = fdot2(wg[k * 4 + 2], hq.z, agv);
            agv = fdot2(wg[k * 4 + 3], hq.w, agv);
            ao  = fdot2(wo_r[r + 0], hq.x, ao);
            ao  = fdot2(wo_r[r + 1], hq.y, ao);
            ao  = fdot2(wo_r[r + 2], hq.z, ao);
            ao  = fdot2(wo_r[r + 3], hq.w, ao);
        }

        if (!q0) {
            float4 p; p.x = ai; p.y = af; p.z = agv; p.w = ao;
            *(float4*)(&pex[hd][0]) = p;
        }
        __syncthreads();

        if (q0) {
            float4 px = *(const float4*)(&pex[hd][0]);
            ai += px.x; af += px.y; agv += px.z; ao += px.w;

            ai += h2f(cg.x); af += h2f(cg.y); agv += h2f(cg.z); ao += h2f(cg.w);

            float si = __builtin_amdgcn_rcpf(1.f + __expf(-ai));
            float sf = __builtin_amdgcn_rcpf(1.f + __expf(-af));
            float so = __builtin_amdgcn_rcpf(1.f + __expf(-ao));
            float eg = __expf(2.f * agv);
            float tg = (eg - 1.f) * __builtin_amdgcn_rcpf(eg + 1.f);
            c = sf * c + si * tg;
            float ec = __expf(2.f * c);
            float tc = (ec - 1.f) * __builtin_amdgcn_rcpf(ec + 1.f);
            h = so * tc;

            ushort hh = f2h(h);
            hs[hd] = hh;
            hb[(size_t)tl * H_ + hd] = hh;
            cg = ng;
        }
        __syncthreads();
    }

    if (q0) {
        state[b * H_ + hd]           = c;
        state[B_ * H_ + b * H_ + hd] = h;
    }
}

// ---------------------------------------------------------------------------
// out[b,t] = sum_hd h[b,t,hd] * Wo[hd] + bo.  h f16 rows, fully dense reads.
// ---------------------------------------------------------------------------
__global__ __launch_bounds__(256) void proj_kernel(
    const ushort* __restrict__ hbuf, const float* __restrict__ Wo,
    const float* __restrict__ bo, float* __restrict__ out, int t0, int TCc) {

    const int lane = threadIdx.x & 63;
    const int wid  = blockIdx.x * 4 + (threadIdx.x >> 6);
    const int nw   = gridDim.x * 4;
    const int rows = B_ * TCc;

    float4 w = *(const float4*)(Wo + lane * 4);
    const float bov = bo[0];

    for (int r = wid; r < rows; r += nw) {
        const ushort* hp = hbuf + (size_t)r * H_ + lane * 4;
        ushort4 u = *(const ushort4*)hp;
        float p = h2f(u.x) * w.x + h2f(u.y) * w.y + h2f(u.z) * w.z + h2f(u.w) * w.w;
#pragma unroll
        for (int m = 1; m < 64; m <<= 1) p += __shfl_xor(p, m, 64);
        if (lane == 0) {
            int b  = r / TCc;
            int tl = r - b * TCc;
            out[(size_t)b * T_ + t0 + tl] = p + bov;
        }
    }
}

// ---------------------------------------------------------------------------
extern "C" void kernel_launch(void* const* d_in, const int* in_sizes, int n_in,
                              void* d_out, int out_size, void* d_ws, size_t ws_size,
                              hipStream_t stream) {
    const float* x   = (const float*)d_in[0];
    const float* Wih = (const float*)d_in[1];
    const float* Whh = (const float*)d_in[2];
    const float* bih = (const float*)d_in[3];
    const float* bhh = (const float*)d_in[4];
    const float* Wo  = (const float*)d_in[5];
    const float* bo  = (const float*)d_in[6];
    float* out = (float*)d_out;

    char* ws = (char*)d_ws;
    ushort* wpk   = (ushort*)ws;                              // 512 KB
    float*  state = (float*)(ws + 512 * 1024);                // 128 KB
    char*   dyn   = ws + 640 * 1024;                          // gx2 + hbuf chunks

    size_t avail = (ws_size > 640 * 1024) ? ws_size - 640 * 1024 : 0;
    // per (b,t): gx2 row 2048 B + hbuf row 512 B
    long long tcmax = (long long)(avail / ((size_t)B_ * (G4_ + H_) * 2));
    // Cap chunks at 512 steps so gx2 (64MB) + hbuf (16MB) stay L3-resident.
    int TC = (tcmax > 512) ? 512 : (int)tcmax;
    TC &= ~63;               // multiple of 64
    if (TC < 64) TC = 64;    // minimum viable chunk

    repack_kernel<<<1024, 256, 0, stream>>>(Whh, wpk);

    for (int t0 = 0; t0 < T_; t0 += TC) {
        int TCc = (T_ - t0 < TC) ? (T_ - t0) : TC;
        ushort* gxb  = (ushort*)dyn;
        ushort* hbuf = (ushort*)(dyn + (size_t)B_ * TCc * G4_ * 2);
        dim3 g1((B_ * TCc) / 32, 4);
        gx_kernel<<<g1, 256, 0, stream>>>(x, Wih, bih, bhh, gxb, t0, TCc);
        lstm_kernel<<<B_, 512, 0, stream>>>(wpk, gxb, hbuf, state, TCc, t0 == 0 ? 1 : 0);
        proj_kernel<<<256, 256, 0, stream>>>(hbuf, Wo, bo, out, t0, TCc);
    }
    (void)in_sizes; (void)n_in; (void)out_size;
}

// Round 8
// 3326.743 us; speedup vs baseline: 1.3533x; 1.1300x over previous
//
#include <hip/hip_runtime.h>
#include <hip/hip_fp16.h>

#define B_  64
#define T_  2048
#define I_  64
#define H_  256
#define G4_ 1024   // 4*H

typedef _Float16 h2v __attribute__((ext_vector_type(2)));

__device__ __forceinline__ float fdot2(uint32_t a, uint32_t b, float c) {
#if __has_builtin(__builtin_amdgcn_fdot2)
    return __builtin_amdgcn_fdot2(__builtin_bit_cast(h2v, a), __builtin_bit_cast(h2v, b), c, false);
#else
    h2v ha = __builtin_bit_cast(h2v, a), hb = __builtin_bit_cast(h2v, b);
    return c + (float)ha.x * (float)hb.x + (float)ha.y * (float)hb.y;
#endif
}

__device__ __forceinline__ ushort f2h(float v) {
    return __builtin_bit_cast(ushort, (_Float16)v);
}
__device__ __forceinline__ float h2f(ushort v) {
    return (float)__builtin_bit_cast(_Float16, v);
}

// ---------------------------------------------------------------------------
// Repack W_hh fp32 [1024][256] -> f16 wpk[g][kc][h][j]  (g=gate, kc=K/8 chunk,
// h=hdim 0..255, j=0..7).  Coalesced 16B/lane preload in the LSTM kernel.
// ---------------------------------------------------------------------------
__global__ void repack_kernel(const float* __restrict__ Whh, ushort* __restrict__ wpk) {
    int o  = blockIdx.x * 256 + threadIdx.x;   // 0 .. 262143
    int j  = o & 7;
    int h  = (o >> 3) & 255;
    int kc = (o >> 11) & 31;
    int g  = o >> 16;
    float v = Whh[(g * 256 + h) * 256 + kc * 8 + j];
    wpk[o] = f2h(v);
}

// ---------------------------------------------------------------------------
// gx2 = x @ W_ih^T + b_ih + b_hh, TRANSPOSED f16 layout [bt][hd][gate] so the
// lstm kernel fetches one ushort4 per (t,hd).  grid = ((64*TCc)/32, 4).
// ---------------------------------------------------------------------------
__global__ __launch_bounds__(256) void gx_kernel(
    const float* __restrict__ x, const float* __restrict__ Wih,
    const float* __restrict__ bih, const float* __restrict__ bhh,
    ushort* __restrict__ gx2, int t0, int TCc) {

    __shared__ float xs[32][64];
    const int bt0 = blockIdx.x * 32;
    const int gq  = blockIdx.y;                 // gate 0..3 (i,f,g,o)
    const int row = gq * 256 + threadIdx.x;     // W_ih row

    for (int i = threadIdx.x; i < 512; i += 256) {
        int r  = i >> 4, c4 = i & 15;
        int bt = bt0 + r;
        int b  = bt / TCc;
        int tl = bt - b * TCc;
        *(float4*)(&xs[r][c4 * 4]) =
            *(const float4*)(&x[(((size_t)b * T_) + t0 + tl) * I_ + c4 * 4]);
    }
    __syncthreads();

    float w[64];
#pragma unroll
    for (int k = 0; k < 64; ++k) w[k] = Wih[row * I_ + k];
    const float bias = bih[row] + bhh[row];

    for (int i = 0; i < 32; ++i) {
        float acc = bias;
#pragma unroll
        for (int k4 = 0; k4 < 16; ++k4) {
            float4 xq = *(const float4*)(&xs[i][k4 * 4]);
            acc = fmaf(w[k4 * 4 + 0], xq.x, acc);
            acc = fmaf(w[k4 * 4 + 1], xq.y, acc);
            acc = fmaf(w[k4 * 4 + 2], xq.z, acc);
            acc = fmaf(w[k4 * 4 + 3], xq.w, acc);
        }
        gx2[((size_t)(bt0 + i) * 256 + threadIdx.x) * 4 + gq] = f2h(acc);
    }
}

// ---------------------------------------------------------------------------
// Persistent per-batch LSTM.  64 blocks x 512 threads.
// __launch_bounds__(512, 1): the ONLY attribute form that has ever yielded
// >128 arch VGPRs (r1: LB(256,1) -> 228).  flat_work_group_size alone (r7)
// and waves_per_eu(N,N) (r3/r6) all produced a 128/128 arch/acc split of the
// 256-total per-wave budget -> accvgpr-move tax ~1200 cyc/step.
// Register demand ~= 200 weight dwords (i/f/g 192 + o 2kc 8) + ~35 working
// ~= 235 <= 256 total, leaving slack so 8 waves x total <= 2048 still fits.
// LDS: o-gate kc 0..13 per half, [kc'][q][hd][8] 1KB-contiguous wave reads
// (0 conflicts, r4-r7).  q=1 hands partials to q=0 via packed float4.
// ---------------------------------------------------------------------------
__global__ __launch_bounds__(512, 1)
void lstm_kernel(
    const ushort* __restrict__ wpk, const ushort* __restrict__ gx2,
    ushort* __restrict__ hbuf,     // [B][TCc][H] f16
    float* __restrict__ state,     // [2][64][256]: c then h
    int TCc, int first) {

    __shared__ __align__(16) ushort wg4[14 * 2 * 256 * 8]; // o-gate stream, 112 KB
    __shared__ __align__(16) ushort hs[256];               // h(t-1) as f16
    __shared__ __align__(16) float pex[256][4];            // q=1 -> q=0 partials

    const int tid   = threadIdx.x;
    const int hd    = tid & 255;       // owned h-dim
    const int q     = tid >> 8;        // K-half: 0 -> kc 0..15, 1 -> kc 16..31
    const int kbase = q << 4;
    const int b     = blockIdx.x;
    const bool q0   = (q == 0);

    // --- preload i/f/g gate half-rows into registers (16B/lane, coalesced) ---
    uint32_t wi[64], wf[64], wg[64];
#pragma unroll
    for (int k = 0; k < 16; ++k) {
        uint4 v = *(const uint4*)(wpk + (size_t)(0 * 32 + kbase + k) * 2048 + hd * 8);
        wi[k * 4 + 0] = v.x; wi[k * 4 + 1] = v.y; wi[k * 4 + 2] = v.z; wi[k * 4 + 3] = v.w;
    }
#pragma unroll
    for (int k = 0; k < 16; ++k) {
        uint4 v = *(const uint4*)(wpk + (size_t)(1 * 32 + kbase + k) * 2048 + hd * 8);
        wf[k * 4 + 0] = v.x; wf[k * 4 + 1] = v.y; wf[k * 4 + 2] = v.z; wf[k * 4 + 3] = v.w;
    }
#pragma unroll
    for (int k = 0; k < 16; ++k) {
        uint4 v = *(const uint4*)(wpk + (size_t)(2 * 32 + kbase + k) * 2048 + hd * 8);
        wg[k * 4 + 0] = v.x; wg[k * 4 + 1] = v.y; wg[k * 4 + 2] = v.z; wg[k * 4 + 3] = v.w;
    }
    // --- o-gate: kc 0..13 -> LDS [kc'][q][hd][8]; kc 14..15 -> registers ---
#pragma unroll
    for (int k = 0; k < 14; ++k) {
        uint4 v = *(const uint4*)(wpk + (size_t)(3 * 32 + kbase + k) * 2048 + hd * 8);
        *(uint4*)(wg4 + ((k * 2 + q) * 256 + hd) * 8) = v;
    }
    uint32_t wo_r[8];
#pragma unroll
    for (int k = 0; k < 2; ++k) {
        uint4 v = *(const uint4*)(wpk + (size_t)(3 * 32 + kbase + 14 + k) * 2048 + hd * 8);
        wo_r[k * 4 + 0] = v.x; wo_r[k * 4 + 1] = v.y; wo_r[k * 4 + 2] = v.z; wo_r[k * 4 + 3] = v.w;
    }

    float c = 0.f, h = 0.f;
    if (q0) {
        if (!first) {
            c = state[b * H_ + hd];
            h = state[B_ * H_ + b * H_ + hd];
        }
        hs[hd] = f2h(h);
    }
    __syncthreads();

    const ushort* gxb = gx2 + (size_t)b * TCc * G4_;
    ushort* hb = hbuf + (size_t)b * TCc * H_;

    ushort4 cg;
    if (q0) cg = *(const ushort4*)(gxb + (size_t)0 * G4_ + hd * 4);

    for (int tl = 0; tl < TCc; ++tl) {
        // prefetch next step's gates (q0 only; hidden under the dot loop)
        ushort4 ng;
        if (q0) {
            const int tn = (tl + 1 < TCc) ? tl + 1 : tl;
            ng = *(const ushort4*)(gxb + (size_t)tn * G4_ + hd * 4);
        }

        float ai = 0.f, af = 0.f, agv = 0.f, ao = 0.f;

        // --- kc 0..13 of this half: o-weights stream from LDS ---
#pragma unroll
        for (int k = 0; k < 14; ++k) {
            const int kc = kbase + k;
            uint4 hq = *(const uint4*)(hs + kc * 8);                        // bcast
            uint4 wo = *(const uint4*)(wg4 + ((k * 2 + q) * 256 + hd) * 8); // stream
            ai  = fdot2(wi[k * 4 + 0], hq.x, ai);
            ai  = fdot2(wi[k * 4 + 1], hq.y, ai);
            ai  = fdot2(wi[k * 4 + 2], hq.z, ai);
            ai  = fdot2(wi[k * 4 + 3], hq.w, ai);
            af  = fdot2(wf[k * 4 + 0], hq.x, af);
            af  = fdot2(wf[k * 4 + 1], hq.y, af);
            af  = fdot2(wf[k * 4 + 2], hq.z, af);
            af  = fdot2(wf[k * 4 + 3], hq.w, af);
            agv = fdot2(wg[k * 4 + 0], hq.x, agv);
            agv = fdot2(wg[k * 4 + 1], hq.y, agv);
            agv = fdot2(wg[k * 4 + 2], hq.z, agv);
            agv = fdot2(wg[k * 4 + 3], hq.w, agv);
            ao  = fdot2(wo.x, hq.x, ao);
            ao  = fdot2(wo.y, hq.y, ao);
            ao  = fdot2(wo.z, hq.z, ao);
            ao  = fdot2(wo.w, hq.w, ao);
        }
        // --- kc 14..15 of this half: o-weights from registers ---
#pragma unroll
        for (int k = 14; k < 16; ++k) {
            const int kc = kbase + k;
            const int r  = (k - 14) * 4;
            uint4 hq = *(const uint4*)(hs + kc * 8);
            ai  = fdot2(wi[k * 4 + 0], hq.x, ai);
            ai  = fdot2(wi[k * 4 + 1], hq.y, ai);
            ai  = fdot2(wi[k * 4 + 2], hq.z, ai);
            ai  = fdot2(wi[k * 4 + 3], hq.w, ai);
            af  = fdot2(wf[k * 4 + 0], hq.x, af);
            af  = fdot2(wf[k * 4 + 1], hq.y, af);
            af  = fdot2(wf[k * 4 + 2], hq.z, af);
            af  = fdot2(wf[k * 4 + 3], hq.w, af);
            agv = fdot2(wg[k * 4 + 0], hq.x, agv);
            agv = fdot2(wg[k * 4 + 1], hq.y, agv);
            agv = fdot2(wg[k * 4 + 2], hq.z, agv);
            agv = fdot2(wg[k * 4 + 3], hq.w, agv);
            ao  = fdot2(wo_r[r + 0], hq.x, ao);
            ao  = fdot2(wo_r[r + 1], hq.y, ao);
            ao  = fdot2(wo_r[r + 2], hq.z, ao);
            ao  = fdot2(wo_r[r + 3], hq.w, ao);
        }

        if (!q0) {
            float4 p; p.x = ai; p.y = af; p.z = agv; p.w = ao;
            *(float4*)(&pex[hd][0]) = p;
        }
        __syncthreads();

        if (q0) {
            float4 px = *(const float4*)(&pex[hd][0]);
            ai += px.x; af += px.y; agv += px.z; ao += px.w;

            ai += h2f(cg.x); af += h2f(cg.y); agv += h2f(cg.z); ao += h2f(cg.w);

            float si = __builtin_amdgcn_rcpf(1.f + __expf(-ai));
            float sf = __builtin_amdgcn_rcpf(1.f + __expf(-af));
            float so = __builtin_amdgcn_rcpf(1.f + __expf(-ao));
            float eg = __expf(2.f * agv);
            float tg = (eg - 1.f) * __builtin_amdgcn_rcpf(eg + 1.f);
            c = sf * c + si * tg;
            float ec = __expf(2.f * c);
            float tc = (ec - 1.f) * __builtin_amdgcn_rcpf(ec + 1.f);
            h = so * tc;

            ushort hh = f2h(h);
            hs[hd] = hh;
            hb[(size_t)tl * H_ + hd] = hh;
            cg = ng;
        }
        __syncthreads();
    }

    if (q0) {
        state[b * H_ + hd]           = c;
        state[B_ * H_ + b * H_ + hd] = h;
    }
}

// ---------------------------------------------------------------------------
// out[b,t] = sum_hd h[b,t,hd] * Wo[hd] + bo.  h f16 rows, fully dense reads.
// ---------------------------------------------------------------------------
__global__ __launch_bounds__(256) void proj_kernel(
    const ushort* __restrict__ hbuf, const float* __restrict__ Wo,
    const float* __restrict__ bo, float* __restrict__ out, int t0, int TCc) {

    const int lane = threadIdx.x & 63;
    const int wid  = blockIdx.x * 4 + (threadIdx.x >> 6);
    const int nw   = gridDim.x * 4;
    const int rows = B_ * TCc;

    float4 w = *(const float4*)(Wo + lane * 4);
    const float bov = bo[0];

    for (int r = wid; r < rows; r += nw) {
        const ushort* hp = hbuf + (size_t)r * H_ + lane * 4;
        ushort4 u = *(const ushort4*)hp;
        float p = h2f(u.x) * w.x + h2f(u.y) * w.y + h2f(u.z) * w.z + h2f(u.w) * w.w;
#pragma unroll
        for (int m = 1; m < 64; m <<= 1) p += __shfl_xor(p, m, 64);
        if (lane == 0) {
            int b  = r / TCc;
            int tl = r - b * TCc;
            out[(size_t)b * T_ + t0 + tl] = p + bov;
        }
    }
}

// ---------------------------------------------------------------------------
extern "C" void kernel_launch(void* const* d_in, const int* in_sizes, int n_in,
                              void* d_out, int out_size, void* d_ws, size_t ws_size,
                              hipStream_t stream) {
    const float* x   = (const float*)d_in[0];
    const float* Wih = (const float*)d_in[1];
    const float* Whh = (const float*)d_in[2];
    const float* bih = (const float*)d_in[3];
    const float* bhh = (const float*)d_in[4];
    const float* Wo  = (const float*)d_in[5];
    const float* bo  = (const float*)d_in[6];
    float* out = (float*)d_out;

    char* ws = (char*)d_ws;
    ushort* wpk   = (ushort*)ws;                              // 512 KB
    float*  state = (float*)(ws + 512 * 1024);                // 128 KB
    char*   dyn   = ws + 640 * 1024;                          // gx2 + hbuf chunks

    size_t avail = (ws_size > 640 * 1024) ? ws_size - 640 * 1024 : 0;
    // per (b,t): gx2 row 2048 B + hbuf row 512 B
    long long tcmax = (long long)(avail / ((size_t)B_ * (G4_ + H_) * 2));
    // Cap chunks at 512 steps so gx2 (64MB) + hbuf (16MB) stay L3-resident.
    int TC = (tcmax > 512) ? 512 : (int)tcmax;
    TC &= ~63;               // multiple of 64
    if (TC < 64) TC = 64;    // minimum viable chunk

    repack_kernel<<<1024, 256, 0, stream>>>(Whh, wpk);

    for (int t0 = 0; t0 < T_; t0 += TC) {
        int TCc = (T_ - t0 < TC) ? (T_ - t0) : TC;
        ushort* gxb  = (ushort*)dyn;
        ushort* hbuf = (ushort*)(dyn + (size_t)B_ * TCc * G4_ * 2);
        dim3 g1((B_ * TCc) / 32, 4);
        gx_kernel<<<g1, 256, 0, stream>>>(x, Wih, bih, bhh, gxb, t0, TCc);
        lstm_kernel<<<B_, 512, 0, stream>>>(wpk, gxb, hbuf, state, TCc, t0 == 0 ? 1 : 0);
        proj_kernel<<<256, 256, 0, stream>>>(hbuf, Wo, bo, out, t0, TCc);
    }
    (void)in_sizes; (void)n_in; (void)out_size;
}